// Round 7
// baseline (251.116 us; speedup 1.0000x reference)
//
#include <hip/hip_runtime.h>
#include <hip/hip_cooperative_groups.h>

namespace cg = cooperative_groups;

typedef __attribute__((ext_vector_type(8))) short short8;
typedef __attribute__((ext_vector_type(16))) float floatx16;

// B1 frag layout: per sid, q = (ds*9 + j)*4 + nc  (ds in [0,16), j in [0,9), nc in [0,4))
//   uint4 slot = q*128 + p*64 + l   (p = 0 hi, 1 lo; l = lane)
// B2 frag layout: per sid, q2 = (w*9 + j)*2 + nc (w in [0,8), nc in [0,2))
//   uint4 slot = q2*128 + p*64 + l

__device__ __forceinline__ unsigned short f2bf(float f) {
  union { float f; unsigned u; } v; v.f = f;
  unsigned r = v.u + 0x7fffu + ((v.u >> 16) & 1u);
  return (unsigned short)(r >> 16);
}
__device__ __forceinline__ float bf2f(unsigned short h) {
  union { unsigned u; float f; } v; v.u = ((unsigned)h) << 16;
  return v.f;
}

struct Params {
  const float *Xx, *Xy;
  const float *bw1x, *sw1x, *bb1x, *sb1x, *bw2x, *sw2x, *bb2x, *sb2x;
  const float *bw1y, *sw1y, *bb1y, *sb1y, *bw2y, *sw2y, *bb2y, *sb2y;
  const float *finw, *finb;
  uint4 *B1fx, *B1fy, *B2fx, *B2fy;
  float *hp, *b1x, *b1y, *b2x, *b2y, *out;
};

__global__ __launch_bounds__(512, 2) void mega_kernel(Params P)
{
  __shared__ __align__(16) char smem[99328];
  float* xsh = (float*)smem;              // phase1: 64*132 floats = 33792 B
  float* S0  = (float*)(smem + 33792);    // 32 KB
  float* S1  = (float*)(smem + 66560);    // 32 KB
  float* h1s = (float*)smem;              // phase2: 32*136 floats = 17408 B
  float* redw = (float*)(smem + 17408);   // 8 floats

  cg::grid_group grid = cg::this_grid();

  const int t   = threadIdx.x;
  const int bid = blockIdx.x;

  // ================= section 0: prep (one pass, 92544 tasks) =================
  {
    int idx = bid * 512 + t;
    if (idx < 2 * 36864) {                       // B1: 2 sids x 576 q x 64 l
      int sid = idx / 36864;
      int rem = idx - sid * 36864;
      int q = rem >> 6, l = rem & 63;
      int nc = q & 3, t9 = q >> 2;
      int j = t9 % 9, ds = t9 / 9;
      const float* bw = sid ? P.bw1y : P.bw1x;
      const float* sw = sid ? P.sw1y : P.sw1x;
      uint4* dst = sid ? P.B1fy : P.B1fx;
      int o = nc * 32 + (l & 31);
      int dbase = ds * 16 + (l >> 5) * 8;
      unsigned short eh[8], el[8];
      #pragma unroll
      for (int i = 0; i < 8; ++i) {
        int d = dbase + i;
        float wv = (j == 0) ? bw[o * 256 + d] : sw[o * 2048 + d * 8 + (j - 1)];
        unsigned short hi = f2bf(wv);
        eh[i] = hi;
        el[i] = f2bf(wv - bf2f(hi));
      }
      uint4 oh, ol;
      oh.x = (unsigned)eh[0] | ((unsigned)eh[1] << 16);
      oh.y = (unsigned)eh[2] | ((unsigned)eh[3] << 16);
      oh.z = (unsigned)eh[4] | ((unsigned)eh[5] << 16);
      oh.w = (unsigned)eh[6] | ((unsigned)eh[7] << 16);
      ol.x = (unsigned)el[0] | ((unsigned)el[1] << 16);
      ol.y = (unsigned)el[2] | ((unsigned)el[3] << 16);
      ol.z = (unsigned)el[4] | ((unsigned)el[5] << 16);
      ol.w = (unsigned)el[6] | ((unsigned)el[7] << 16);
      dst[q * 128 + l]      = oh;
      dst[q * 128 + 64 + l] = ol;
    } else if (idx < 2 * 36864 + 2 * 9216) {     // B2: 2 sids x 144 q2 x 64 l
      int i2 = idx - 2 * 36864;
      int sid = i2 / 9216;
      int rem = i2 - sid * 9216;
      int q2 = rem >> 6, l = rem & 63;
      int nc = q2 & 1, t9 = q2 >> 1;
      int j = t9 % 9, w = t9 / 9;
      const float* bw = sid ? P.bw2y : P.bw2x;
      const float* sw = sid ? P.sw2y : P.sw2x;
      uint4* dst = sid ? P.B2fy : P.B2fx;
      int o = nc * 32 + (l & 31);
      int dbase = w * 16 + (l >> 5) * 8;
      unsigned short eh[8], el[8];
      #pragma unroll
      for (int i = 0; i < 8; ++i) {
        int d = dbase + i;
        float wv = (j == 0) ? bw[o * 128 + d] : sw[o * 1024 + d * 8 + (j - 1)];
        unsigned short hi = f2bf(wv);
        eh[i] = hi;
        el[i] = f2bf(wv - bf2f(hi));
      }
      uint4 oh, ol;
      oh.x = (unsigned)eh[0] | ((unsigned)eh[1] << 16);
      oh.y = (unsigned)eh[2] | ((unsigned)eh[3] << 16);
      oh.z = (unsigned)eh[4] | ((unsigned)eh[5] << 16);
      oh.w = (unsigned)eh[6] | ((unsigned)eh[7] << 16);
      ol.x = (unsigned)el[0] | ((unsigned)el[1] << 16);
      ol.y = (unsigned)el[2] | ((unsigned)el[3] << 16);
      ol.z = (unsigned)el[4] | ((unsigned)el[5] << 16);
      ol.w = (unsigned)el[6] | ((unsigned)el[7] << 16);
      dst[q2 * 128 + l]      = oh;
      dst[q2 * 128 + 64 + l] = ol;
    } else {
      int i2 = idx - (2 * 36864 + 2 * 9216);
      if (i2 < 128)      P.b1x[i2]       = P.bb1x[i2]       + P.sb1x[i2];
      else if (i2 < 256) P.b1y[i2 - 128] = P.bb1y[i2 - 128] + P.sb1y[i2 - 128];
      else if (i2 < 320) P.b2x[i2 - 256] = P.bb2x[i2 - 256] + P.sb2x[i2 - 256];
      else if (i2 < 384) P.b2y[i2 - 320] = P.bb2y[i2 - 320] + P.sb2y[i2 - 320];
    }
  }
  __threadfence();
  grid.sync();

  // ================= section 1: layer1, block = (sid, m 64-row tile, K-half s)
  {
    const int sid  = bid >> 7;
    const int rem  = bid & 127;
    const int m    = rem >> 1;
    const int s    = rem & 1;
    const int wave = t >> 6;
    const int l    = t & 63;
    const int lc   = l & 31;
    const int lk   = l >> 5;

    const float* X  = sid ? P.Xy : P.Xx;
    const uint4* B1 = sid ? P.B1fy : P.B1fx;

    // stage 64 rows x 128 cols (this block's K-half), coalesced
    {
      int r = t >> 3, c8 = (t & 7) * 16;
      const float* src = X + (size_t)(m * 64 + r) * 256 + s * 128 + c8;
      #pragma unroll
      for (int q = 0; q < 4; ++q)
        *(float4*)(xsh + r * 132 + c8 + q * 4) = *(const float4*)(src + q * 4);
    }
    __syncthreads();

    float xr0[8], xr1[8];
    {
      int cb = wave * 16 + lk * 8;
      float4 v0 = *(const float4*)(xsh + lc * 132 + cb);
      float4 v1 = *(const float4*)(xsh + lc * 132 + cb + 4);
      float4 u0 = *(const float4*)(xsh + (lc + 32) * 132 + cb);
      float4 u1 = *(const float4*)(xsh + (lc + 32) * 132 + cb + 4);
      xr0[0]=v0.x; xr0[1]=v0.y; xr0[2]=v0.z; xr0[3]=v0.w;
      xr0[4]=v1.x; xr0[5]=v1.y; xr0[6]=v1.z; xr0[7]=v1.w;
      xr1[0]=u0.x; xr1[1]=u0.y; xr1[2]=u0.z; xr1[3]=u0.w;
      xr1[4]=u1.x; xr1[5]=u1.y; xr1[6]=u1.z; xr1[7]=u1.w;
    }

    floatx16 acc[2][4] = {};
    const int ds = s * 8 + wave;
    const uint4* bbase = B1 + (size_t)(ds * 9 * 4) * 128 + l;   // j stride = 512 uint4

    auto l1step = [&](int j, const uint4* bf) {
      float f0[8], f1[8];
      if (j == 0) {
        #pragma unroll
        for (int i = 0; i < 8; ++i) {
          f0[i] = __fdividef(xr0[i], 1.f + __expf(-xr0[i]));
          f1[i] = __fdividef(xr1[i], 1.f + __expf(-xr1[i]));
        }
      } else {
        float g = -2.f + (float)(j - 1) * (4.f / 7.f);
        #pragma unroll
        for (int i = 0; i < 8; ++i) {
          float z0 = (xr0[i] - g) * 1.75f;
          float z1 = (xr1[i] - g) * 1.75f;
          f0[i] = __expf(-z0 * z0);
          f1[i] = __expf(-z1 * z1);
        }
      }
      short8 a0, a1;
      #pragma unroll
      for (int i = 0; i < 8; ++i) {
        a0[i] = (short)f2bf(f0[i]);
        a1[i] = (short)f2bf(f1[i]);
      }
      #pragma unroll
      for (int nc = 0; nc < 4; ++nc) {
        short8 bh = __builtin_bit_cast(short8, bf[nc * 2]);
        short8 bl = __builtin_bit_cast(short8, bf[nc * 2 + 1]);
        acc[0][nc] = __builtin_amdgcn_mfma_f32_32x32x16_bf16(a0, bh, acc[0][nc], 0, 0, 0);
        acc[0][nc] = __builtin_amdgcn_mfma_f32_32x32x16_bf16(a0, bl, acc[0][nc], 0, 0, 0);
        acc[1][nc] = __builtin_amdgcn_mfma_f32_32x32x16_bf16(a1, bh, acc[1][nc], 0, 0, 0);
        acc[1][nc] = __builtin_amdgcn_mfma_f32_32x32x16_bf16(a1, bl, acc[1][nc], 0, 0, 0);
      }
    };

    uint4 bfA[8], bfB[8];
    #pragma unroll
    for (int nc = 0; nc < 4; ++nc) { bfA[nc*2] = bbase[nc*128]; bfA[nc*2+1] = bbase[nc*128 + 64]; }

    #pragma unroll 1
    for (int jj = 0; jj < 4; ++jj) {
      const int j0 = jj * 2;
      {
        const uint4* bp = bbase + (size_t)(j0 + 1) * 512;
        #pragma unroll
        for (int nc = 0; nc < 4; ++nc) { bfB[nc*2] = bp[nc*128]; bfB[nc*2+1] = bp[nc*128 + 64]; }
      }
      l1step(j0, bfA);
      {
        const uint4* bp = bbase + (size_t)(j0 + 2) * 512;
        #pragma unroll
        for (int nc = 0; nc < 4; ++nc) { bfA[nc*2] = bp[nc*128]; bfA[nc*2+1] = bp[nc*128 + 64]; }
      }
      l1step(j0 + 1, bfB);
    }
    l1step(8, bfA);

    // cross-wave K reduction: race-free 2-buffer tree
    auto st = [&](float* Sb) {
      #pragma unroll
      for (int g = 0; g < 2; ++g)
        #pragma unroll
        for (int nc = 0; nc < 4; ++nc)
          #pragma unroll
          for (int r = 0; r < 16; ++r) {
            int row = g * 32 + (r & 3) + 8 * (r >> 2) + 4 * lk;
            Sb[row * 128 + nc * 32 + lc] = acc[g][nc][r];
          }
    };
    auto ad = [&](const float* Sb) {
      #pragma unroll
      for (int g = 0; g < 2; ++g)
        #pragma unroll
        for (int nc = 0; nc < 4; ++nc)
          #pragma unroll
          for (int r = 0; r < 16; ++r) {
            int row = g * 32 + (r & 3) + 8 * (r >> 2) + 4 * lk;
            acc[g][nc][r] += Sb[row * 128 + nc * 32 + lc];
          }
    };
    __syncthreads();
    if (wave == 1) st(S0);
    if (wave == 3) st(S1);
    __syncthreads();
    if (wave == 0) ad(S0);
    if (wave == 2) ad(S1);
    __syncthreads();
    if (wave == 5) st(S0);
    if (wave == 7) st(S1);
    __syncthreads();
    if (wave == 4) ad(S0);
    if (wave == 6) ad(S1);
    __syncthreads();
    if (wave == 2) st(S0);
    if (wave == 6) st(S1);
    __syncthreads();
    if (wave == 0) ad(S0);
    if (wave == 4) ad(S1);
    __syncthreads();
    if (wave == 4) st(S0);
    __syncthreads();
    if (wave == 0) { ad(S0); st(S0); }
    __syncthreads();

    // coalesced copy S0 -> hp
    {
      float* dst = P.hp + (size_t)((sid * 2 + s) * 524288 + m * 8192);
      #pragma unroll
      for (int q = 0; q < 4; ++q)
        *(float4*)(dst + t * 16 + q * 4) = *(const float4*)(S0 + t * 16 + q * 4);
    }
  }
  __threadfence();
  grid.sync();

  // ================= section 2: layer2 + final dot + atomic finish ===========
  {
    const int sid  = bid >> 7;
    const int m2   = bid & 127;
    const int wave = t >> 6;
    const int l    = t & 63;
    const int lc   = l & 31;
    const int lk   = l >> 5;

    const uint4* B2 = sid ? P.B2fy : P.B2fx;
    const float* b1 = sid ? P.b1y : P.b1x;
    const float* b2 = sid ? P.b2y : P.b2x;

    // h1 = hp_half0 + hp_half1 + b1
    {
      const float* hp0 = P.hp + (size_t)((sid * 2 + 0) * 524288 + m2 * 4096);
      const float* hp1 = P.hp + (size_t)((sid * 2 + 1) * 524288 + m2 * 4096);
      int flat = t * 8;
      int row = flat >> 7, cb = flat & 127;
      float4 a0 = *(const float4*)(hp0 + flat);
      float4 a1 = *(const float4*)(hp0 + flat + 4);
      float4 c0 = *(const float4*)(hp1 + flat);
      float4 c1 = *(const float4*)(hp1 + flat + 4);
      h1s[row * 136 + cb + 0] = a0.x + c0.x + b1[cb + 0];
      h1s[row * 136 + cb + 1] = a0.y + c0.y + b1[cb + 1];
      h1s[row * 136 + cb + 2] = a0.z + c0.z + b1[cb + 2];
      h1s[row * 136 + cb + 3] = a0.w + c0.w + b1[cb + 3];
      h1s[row * 136 + cb + 4] = a1.x + c1.x + b1[cb + 4];
      h1s[row * 136 + cb + 5] = a1.y + c1.y + b1[cb + 5];
      h1s[row * 136 + cb + 6] = a1.z + c1.z + b1[cb + 6];
      h1s[row * 136 + cb + 7] = a1.w + c1.w + b1[cb + 7];
    }
    __syncthreads();

    float hr[8];
    {
      int cb = wave * 16 + lk * 8;
      float4 v0 = *(const float4*)(h1s + lc * 136 + cb);
      float4 v1 = *(const float4*)(h1s + lc * 136 + cb + 4);
      hr[0]=v0.x; hr[1]=v0.y; hr[2]=v0.z; hr[3]=v0.w;
      hr[4]=v1.x; hr[5]=v1.y; hr[6]=v1.z; hr[7]=v1.w;
    }

    floatx16 acc2[2] = {};
    const uint4* bbase2 = B2 + (size_t)(wave * 9 * 2) * 128 + l;  // j stride = 256 uint4

    auto l2step = [&](int j, const uint4* bf) {
      float f[8];
      if (j == 0) {
        #pragma unroll
        for (int i = 0; i < 8; ++i)
          f[i] = __fdividef(hr[i], 1.f + __expf(-hr[i]));
      } else {
        float g = -2.f + (float)(j - 1) * (4.f / 7.f);
        #pragma unroll
        for (int i = 0; i < 8; ++i) {
          float z = (hr[i] - g) * 1.75f;
          f[i] = __expf(-z * z);
        }
      }
      short8 ah;
      #pragma unroll
      for (int i = 0; i < 8; ++i) ah[i] = (short)f2bf(f[i]);
      #pragma unroll
      for (int nc = 0; nc < 2; ++nc) {
        short8 bh = __builtin_bit_cast(short8, bf[nc * 2]);
        short8 bl = __builtin_bit_cast(short8, bf[nc * 2 + 1]);
        acc2[nc] = __builtin_amdgcn_mfma_f32_32x32x16_bf16(ah, bh, acc2[nc], 0, 0, 0);
        acc2[nc] = __builtin_amdgcn_mfma_f32_32x32x16_bf16(ah, bl, acc2[nc], 0, 0, 0);
      }
    };

    uint4 cfA[4], cfB[4];
    #pragma unroll
    for (int nc = 0; nc < 2; ++nc) { cfA[nc*2] = bbase2[nc*128]; cfA[nc*2+1] = bbase2[nc*128 + 64]; }
    #pragma unroll 1
    for (int jj = 0; jj < 4; ++jj) {
      const int j0 = jj * 2;
      {
        const uint4* bp = bbase2 + (size_t)(j0 + 1) * 256;
        #pragma unroll
        for (int nc = 0; nc < 2; ++nc) { cfB[nc*2] = bp[nc*128]; cfB[nc*2+1] = bp[nc*128 + 64]; }
      }
      l2step(j0, cfA);
      {
        const uint4* bp = bbase2 + (size_t)(j0 + 2) * 256;
        #pragma unroll
        for (int nc = 0; nc < 2; ++nc) { cfA[nc*2] = bp[nc*128]; cfA[nc*2+1] = bp[nc*128 + 64]; }
      }
      l2step(j0 + 1, cfB);
    }
    l2step(8, cfA);

    const float* wf = P.finw + sid * 64;
    {
      float w0 = wf[lc], w1v = wf[32 + lc];
      float pz = 0.f;
      #pragma unroll
      for (int r = 0; r < 16; ++r) pz += acc2[0][r] * w0 + acc2[1][r] * w1v;
      #pragma unroll
      for (int off = 32; off > 0; off >>= 1) pz += __shfl_down(pz, off, 64);
      if (l == 0) redw[wave] = pz;
    }
    __syncthreads();
    if (wave == 0) {
      float v = (l < 8) ? redw[l] : 0.f;
      v += 32.f * b2[l] * wf[l];      // bias term over this block's 32 rows
      #pragma unroll
      for (int off = 32; off > 0; off >>= 1) v += __shfl_down(v, off, 64);
      if (l == 0) {
        float contrib = v * (1.0f / 1024.0f);
        if (sid == 0 && (m2 & 31) == 0) contrib += P.finb[0];  // finb added once per batch
        atomicAdd(&P.out[m2 >> 5], contrib);
      }
    }
  }
}

extern "C" void kernel_launch(void* const* d_in, const int* in_sizes, int n_in,
                              void* d_out, int out_size, void* d_ws, size_t ws_size,
                              hipStream_t stream)
{
  (void)in_sizes; (void)n_in; (void)out_size; (void)ws_size;
  Params p;
  p.Xx   = (const float*)d_in[0];
  p.Xy   = (const float*)d_in[1];
  p.bw1x = (const float*)d_in[2];
  p.bb1x = (const float*)d_in[3];
  p.sw1x = (const float*)d_in[4];
  p.sb1x = (const float*)d_in[5];
  p.bw2x = (const float*)d_in[6];
  p.bb2x = (const float*)d_in[7];
  p.sw2x = (const float*)d_in[8];
  p.sb2x = (const float*)d_in[9];
  p.bw1y = (const float*)d_in[10];
  p.bb1y = (const float*)d_in[11];
  p.sw1y = (const float*)d_in[12];
  p.sb1y = (const float*)d_in[13];
  p.bw2y = (const float*)d_in[14];
  p.bb2y = (const float*)d_in[15];
  p.sw2y = (const float*)d_in[16];
  p.sb2y = (const float*)d_in[17];
  p.finw = (const float*)d_in[18];
  p.finb = (const float*)d_in[19];

  char* ws = (char*)d_ws;
  p.B1fx = (uint4*)(ws);
  p.B1fy = (uint4*)(ws + 1179648);
  p.B2fx = (uint4*)(ws + 2359296);
  p.B2fy = (uint4*)(ws + 2654208);
  p.hp   = (float*)(ws + 2949120);                 // 8 MB
  p.b1x  = (float*)(ws + 2949120 + 8388608);
  p.b1y  = p.b1x + 128;
  p.b2x  = p.b1y + 128;
  p.b2y  = p.b2x + 64;
  p.out  = (float*)d_out;

  hipMemsetAsync(d_out, 0, 4 * sizeof(float), stream);

  void* args[] = { (void*)&p };
  hipLaunchCooperativeKernel((void*)mega_kernel, dim3(256), dim3(512), args, 0, stream);
}

// Round 8
// 49.110 us; speedup vs baseline: 5.1133x; 5.1133x over previous
//
#include <hip/hip_runtime.h>

typedef __attribute__((ext_vector_type(8))) short short8;
typedef __attribute__((ext_vector_type(16))) float floatx16;

// B1 frag layout: per sid, q = (ds*9 + j)*4 + nc  (ds in [0,16), j in [0,9), nc in [0,4))
//   uint4 slot = q*128 + p*64 + l   (p = 0 hi, 1 lo; l = lane)
// B2 frag layout: per sid, q2 = (w*9 + j)*2 + nc (w in [0,8), nc in [0,2))
//   uint4 slot = q2*128 + p*64 + l

__device__ __forceinline__ unsigned short f2bf(float f) {
  union { float f; unsigned u; } v; v.f = f;
  unsigned r = v.u + 0x7fffu + ((v.u >> 16) & 1u);
  return (unsigned short)(r >> 16);
}
__device__ __forceinline__ float bf2f(unsigned short h) {
  union { unsigned u; float f; } v; v.u = ((unsigned)h) << 16;
  return v.f;
}

__global__ __launch_bounds__(256) void prep_frags(
    const float* __restrict__ bw1x, const float* __restrict__ sw1x,
    const float* __restrict__ bb1x, const float* __restrict__ sb1x,
    const float* __restrict__ bw2x, const float* __restrict__ sw2x,
    const float* __restrict__ bb2x, const float* __restrict__ sb2x,
    const float* __restrict__ bw1y, const float* __restrict__ sw1y,
    const float* __restrict__ bb1y, const float* __restrict__ sb1y,
    const float* __restrict__ bw2y, const float* __restrict__ sw2y,
    const float* __restrict__ bb2y, const float* __restrict__ sb2y,
    uint4* __restrict__ B1fx, uint4* __restrict__ B1fy,
    uint4* __restrict__ B2fx, uint4* __restrict__ B2fy,
    float* __restrict__ b1x, float* __restrict__ b1y,
    float* __restrict__ b2x, float* __restrict__ b2y)
{
  int idx = blockIdx.x * 256 + threadIdx.x;
  if (idx < 2 * 36864) {                       // B1: 2 sids x 576 q x 64 l
    int sid = idx / 36864;
    int rem = idx - sid * 36864;
    int q = rem >> 6, l = rem & 63;
    int nc = q & 3, t9 = q >> 2;
    int j = t9 % 9, ds = t9 / 9;
    const float* bw = sid ? bw1y : bw1x;
    const float* sw = sid ? sw1y : sw1x;
    uint4* dst = sid ? B1fy : B1fx;
    int o = nc * 32 + (l & 31);
    int dbase = ds * 16 + (l >> 5) * 8;
    unsigned short eh[8], el[8];
    #pragma unroll
    for (int i = 0; i < 8; ++i) {
      int d = dbase + i;
      float wv = (j == 0) ? bw[o * 256 + d] : sw[o * 2048 + d * 8 + (j - 1)];
      unsigned short hi = f2bf(wv);
      eh[i] = hi;
      el[i] = f2bf(wv - bf2f(hi));
    }
    uint4 oh, ol;
    oh.x = (unsigned)eh[0] | ((unsigned)eh[1] << 16);
    oh.y = (unsigned)eh[2] | ((unsigned)eh[3] << 16);
    oh.z = (unsigned)eh[4] | ((unsigned)eh[5] << 16);
    oh.w = (unsigned)eh[6] | ((unsigned)eh[7] << 16);
    ol.x = (unsigned)el[0] | ((unsigned)el[1] << 16);
    ol.y = (unsigned)el[2] | ((unsigned)el[3] << 16);
    ol.z = (unsigned)el[4] | ((unsigned)el[5] << 16);
    ol.w = (unsigned)el[6] | ((unsigned)el[7] << 16);
    dst[q * 128 + l]      = oh;
    dst[q * 128 + 64 + l] = ol;
  } else if (idx < 2 * 36864 + 2 * 9216) {     // B2: 2 sids x 144 q2 x 64 l
    int i2 = idx - 2 * 36864;
    int sid = i2 / 9216;
    int rem = i2 - sid * 9216;
    int q2 = rem >> 6, l = rem & 63;
    int nc = q2 & 1, t9 = q2 >> 1;
    int j = t9 % 9, w = t9 / 9;
    const float* bw = sid ? bw2y : bw2x;
    const float* sw = sid ? sw2y : sw2x;
    uint4* dst = sid ? B2fy : B2fx;
    int o = nc * 32 + (l & 31);
    int dbase = w * 16 + (l >> 5) * 8;
    unsigned short eh[8], el[8];
    #pragma unroll
    for (int i = 0; i < 8; ++i) {
      int d = dbase + i;
      float wv = (j == 0) ? bw[o * 128 + d] : sw[o * 1024 + d * 8 + (j - 1)];
      unsigned short hi = f2bf(wv);
      eh[i] = hi;
      el[i] = f2bf(wv - bf2f(hi));
    }
    uint4 oh, ol;
    oh.x = (unsigned)eh[0] | ((unsigned)eh[1] << 16);
    oh.y = (unsigned)eh[2] | ((unsigned)eh[3] << 16);
    oh.z = (unsigned)eh[4] | ((unsigned)eh[5] << 16);
    oh.w = (unsigned)eh[6] | ((unsigned)eh[7] << 16);
    ol.x = (unsigned)el[0] | ((unsigned)el[1] << 16);
    ol.y = (unsigned)el[2] | ((unsigned)el[3] << 16);
    ol.z = (unsigned)el[4] | ((unsigned)el[5] << 16);
    ol.w = (unsigned)el[6] | ((unsigned)el[7] << 16);
    dst[q2 * 128 + l]      = oh;
    dst[q2 * 128 + 64 + l] = ol;
  } else {
    int i2 = idx - (2 * 36864 + 2 * 9216);
    if (i2 < 0) return;
    if (i2 < 128)      b1x[i2]       = bb1x[i2]       + sb1x[i2];
    else if (i2 < 256) b1y[i2 - 128] = bb1y[i2 - 128] + sb1y[i2 - 128];
    else if (i2 < 320) b2x[i2 - 256] = bb2x[i2 - 256] + sb2x[i2 - 256];
    else if (i2 < 384) b2y[i2 - 320] = bb2y[i2 - 320] + sb2y[i2 - 320];
  }
}

// ---------- phase1: layer1, block = (sid, 64-row tile m, K-half s) ----------
__global__ __launch_bounds__(512) void phase1_kernel(
    const float* __restrict__ Xx, const float* __restrict__ Xy,
    const uint4* __restrict__ B1fx, const uint4* __restrict__ B1fy,
    float* __restrict__ hp)
{
  // xsh (33792 B) is dead after the register reads; S0 aliases it.
  __shared__ __align__(16) char smem[66560];
  float* xsh = (float*)smem;              // 64*132 floats
  float* S0  = (float*)smem;              // 32 KB (alias, used after barrier)
  float* S1  = (float*)(smem + 33792);    // 32 KB

  const int t    = threadIdx.x;
  const int bid  = blockIdx.x;
  const int sid  = bid >> 7;
  const int rem  = bid & 127;
  const int m    = rem >> 1;
  const int s    = rem & 1;
  const int wave = t >> 6;
  const int l    = t & 63;
  const int lc   = l & 31;
  const int lk   = l >> 5;

  const float* X  = sid ? Xy : Xx;
  const uint4* B1 = sid ? B1fy : B1fx;

  // stage 64 rows x 128 cols (this block's K-half), coalesced
  {
    int r = t >> 3, c8 = (t & 7) * 16;
    const float* src = X + (size_t)(m * 64 + r) * 256 + s * 128 + c8;
    #pragma unroll
    for (int q = 0; q < 4; ++q)
      *(float4*)(xsh + r * 132 + c8 + q * 4) = *(const float4*)(src + q * 4);
  }
  __syncthreads();

  float xr0[8], xr1[8];
  {
    int cb = wave * 16 + lk * 8;
    float4 v0 = *(const float4*)(xsh + lc * 132 + cb);
    float4 v1 = *(const float4*)(xsh + lc * 132 + cb + 4);
    float4 u0 = *(const float4*)(xsh + (lc + 32) * 132 + cb);
    float4 u1 = *(const float4*)(xsh + (lc + 32) * 132 + cb + 4);
    xr0[0]=v0.x; xr0[1]=v0.y; xr0[2]=v0.z; xr0[3]=v0.w;
    xr0[4]=v1.x; xr0[5]=v1.y; xr0[6]=v1.z; xr0[7]=v1.w;
    xr1[0]=u0.x; xr1[1]=u0.y; xr1[2]=u0.z; xr1[3]=u0.w;
    xr1[4]=u1.x; xr1[5]=u1.y; xr1[6]=u1.z; xr1[7]=u1.w;
  }

  floatx16 acc[2][4] = {};
  const int ds = s * 8 + wave;
  const uint4* bbase = B1 + (size_t)(ds * 9 * 4) * 128 + l;   // j stride = 512 uint4

  auto l1step = [&](int j, const uint4* bf) {
    float f0[8], f1[8];
    if (j == 0) {
      #pragma unroll
      for (int i = 0; i < 8; ++i) {
        f0[i] = __fdividef(xr0[i], 1.f + __expf(-xr0[i]));
        f1[i] = __fdividef(xr1[i], 1.f + __expf(-xr1[i]));
      }
    } else {
      float g = -2.f + (float)(j - 1) * (4.f / 7.f);
      #pragma unroll
      for (int i = 0; i < 8; ++i) {
        float z0 = (xr0[i] - g) * 1.75f;
        float z1 = (xr1[i] - g) * 1.75f;
        f0[i] = __expf(-z0 * z0);
        f1[i] = __expf(-z1 * z1);
      }
    }
    short8 a0, a1;
    #pragma unroll
    for (int i = 0; i < 8; ++i) {
      a0[i] = (short)f2bf(f0[i]);
      a1[i] = (short)f2bf(f1[i]);
    }
    #pragma unroll
    for (int nc = 0; nc < 4; ++nc) {
      short8 bh = __builtin_bit_cast(short8, bf[nc * 2]);
      short8 bl = __builtin_bit_cast(short8, bf[nc * 2 + 1]);
      acc[0][nc] = __builtin_amdgcn_mfma_f32_32x32x16_bf16(a0, bh, acc[0][nc], 0, 0, 0);
      acc[0][nc] = __builtin_amdgcn_mfma_f32_32x32x16_bf16(a0, bl, acc[0][nc], 0, 0, 0);
      acc[1][nc] = __builtin_amdgcn_mfma_f32_32x32x16_bf16(a1, bh, acc[1][nc], 0, 0, 0);
      acc[1][nc] = __builtin_amdgcn_mfma_f32_32x32x16_bf16(a1, bl, acc[1][nc], 0, 0, 0);
    }
  };

  uint4 bfA[8], bfB[8];
  #pragma unroll
  for (int nc = 0; nc < 4; ++nc) { bfA[nc*2] = bbase[nc*128]; bfA[nc*2+1] = bbase[nc*128 + 64]; }

  #pragma unroll 1
  for (int jj = 0; jj < 4; ++jj) {
    const int j0 = jj * 2;
    {
      const uint4* bp = bbase + (size_t)(j0 + 1) * 512;
      #pragma unroll
      for (int nc = 0; nc < 4; ++nc) { bfB[nc*2] = bp[nc*128]; bfB[nc*2+1] = bp[nc*128 + 64]; }
    }
    l1step(j0, bfA);
    {
      const uint4* bp = bbase + (size_t)(j0 + 2) * 512;
      #pragma unroll
      for (int nc = 0; nc < 4; ++nc) { bfA[nc*2] = bp[nc*128]; bfA[nc*2+1] = bp[nc*128 + 64]; }
    }
    l1step(j0 + 1, bfB);
  }
  l1step(8, bfA);

  // cross-wave K reduction: race-free 2-buffer tree (S0 aliases dead xsh)
  auto st = [&](float* Sb) {
    #pragma unroll
    for (int g = 0; g < 2; ++g)
      #pragma unroll
      for (int nc = 0; nc < 4; ++nc)
        #pragma unroll
        for (int r = 0; r < 16; ++r) {
          int row = g * 32 + (r & 3) + 8 * (r >> 2) + 4 * lk;
          Sb[row * 128 + nc * 32 + lc] = acc[g][nc][r];
        }
  };
  auto ad = [&](const float* Sb) {
    #pragma unroll
    for (int g = 0; g < 2; ++g)
      #pragma unroll
      for (int nc = 0; nc < 4; ++nc)
        #pragma unroll
        for (int r = 0; r < 16; ++r) {
          int row = g * 32 + (r & 3) + 8 * (r >> 2) + 4 * lk;
          acc[g][nc][r] += Sb[row * 128 + nc * 32 + lc];
        }
  };
  __syncthreads();
  if (wave == 1) st(S0);
  if (wave == 3) st(S1);
  __syncthreads();
  if (wave == 0) ad(S0);
  if (wave == 2) ad(S1);
  __syncthreads();
  if (wave == 5) st(S0);
  if (wave == 7) st(S1);
  __syncthreads();
  if (wave == 4) ad(S0);
  if (wave == 6) ad(S1);
  __syncthreads();
  if (wave == 2) st(S0);
  if (wave == 6) st(S1);
  __syncthreads();
  if (wave == 0) ad(S0);
  if (wave == 4) ad(S1);
  __syncthreads();
  if (wave == 4) st(S0);
  __syncthreads();
  if (wave == 0) { ad(S0); st(S0); }
  __syncthreads();

  // coalesced copy S0 -> hp
  {
    float* dst = hp + (size_t)((sid * 2 + s) * 524288 + m * 8192);
    #pragma unroll
    for (int q = 0; q < 4; ++q)
      *(float4*)(dst + t * 16 + q * 4) = *(const float4*)(S0 + t * 16 + q * 4);
  }
}

// ---------- phase2: layer2 + final dot + atomic finish ----------
__global__ __launch_bounds__(512) void phase2_kernel(
    const uint4* __restrict__ B2fx, const uint4* __restrict__ B2fy,
    const float* __restrict__ hp,
    const float* __restrict__ b1x_, const float* __restrict__ b1y_,
    const float* __restrict__ b2x_, const float* __restrict__ b2y_,
    const float* __restrict__ finw, const float* __restrict__ finb,
    float* __restrict__ out)
{
  __shared__ float h1s[32 * 136];   // 17.4 KB
  __shared__ float redw[8];

  const int t    = threadIdx.x;
  const int bid  = blockIdx.x;
  const int sid  = bid >> 7;
  const int m2   = bid & 127;
  const int wave = t >> 6;
  const int l    = t & 63;
  const int lc   = l & 31;
  const int lk   = l >> 5;

  const uint4* B2 = sid ? B2fy : B2fx;
  const float* b1 = sid ? b1y_ : b1x_;
  const float* b2 = sid ? b2y_ : b2x_;

  // h1 = hp_half0 + hp_half1 + b1
  {
    const float* hp0 = hp + (size_t)((sid * 2 + 0) * 524288 + m2 * 4096);
    const float* hp1 = hp + (size_t)((sid * 2 + 1) * 524288 + m2 * 4096);
    int flat = t * 8;
    int row = flat >> 7, cb = flat & 127;
    float4 a0 = *(const float4*)(hp0 + flat);
    float4 a1 = *(const float4*)(hp0 + flat + 4);
    float4 c0 = *(const float4*)(hp1 + flat);
    float4 c1 = *(const float4*)(hp1 + flat + 4);
    h1s[row * 136 + cb + 0] = a0.x + c0.x + b1[cb + 0];
    h1s[row * 136 + cb + 1] = a0.y + c0.y + b1[cb + 1];
    h1s[row * 136 + cb + 2] = a0.z + c0.z + b1[cb + 2];
    h1s[row * 136 + cb + 3] = a0.w + c0.w + b1[cb + 3];
    h1s[row * 136 + cb + 4] = a1.x + c1.x + b1[cb + 4];
    h1s[row * 136 + cb + 5] = a1.y + c1.y + b1[cb + 5];
    h1s[row * 136 + cb + 6] = a1.z + c1.z + b1[cb + 6];
    h1s[row * 136 + cb + 7] = a1.w + c1.w + b1[cb + 7];
  }
  __syncthreads();

  float hr[8];
  {
    int cb = wave * 16 + lk * 8;
    float4 v0 = *(const float4*)(h1s + lc * 136 + cb);
    float4 v1 = *(const float4*)(h1s + lc * 136 + cb + 4);
    hr[0]=v0.x; hr[1]=v0.y; hr[2]=v0.z; hr[3]=v0.w;
    hr[4]=v1.x; hr[5]=v1.y; hr[6]=v1.z; hr[7]=v1.w;
  }

  floatx16 acc2[2] = {};
  const uint4* bbase2 = B2 + (size_t)(wave * 9 * 2) * 128 + l;  // j stride = 256 uint4

  auto l2step = [&](int j, const uint4* bf) {
    float f[8];
    if (j == 0) {
      #pragma unroll
      for (int i = 0; i < 8; ++i)
        f[i] = __fdividef(hr[i], 1.f + __expf(-hr[i]));
    } else {
      float g = -2.f + (float)(j - 1) * (4.f / 7.f);
      #pragma unroll
      for (int i = 0; i < 8; ++i) {
        float z = (hr[i] - g) * 1.75f;
        f[i] = __expf(-z * z);
      }
    }
    short8 ah;
    #pragma unroll
    for (int i = 0; i < 8; ++i) ah[i] = (short)f2bf(f[i]);
    #pragma unroll
    for (int nc = 0; nc < 2; ++nc) {
      short8 bh = __builtin_bit_cast(short8, bf[nc * 2]);
      short8 bl = __builtin_bit_cast(short8, bf[nc * 2 + 1]);
      acc2[nc] = __builtin_amdgcn_mfma_f32_32x32x16_bf16(ah, bh, acc2[nc], 0, 0, 0);
      acc2[nc] = __builtin_amdgcn_mfma_f32_32x32x16_bf16(ah, bl, acc2[nc], 0, 0, 0);
    }
  };

  uint4 cfA[4], cfB[4];
  #pragma unroll
  for (int nc = 0; nc < 2; ++nc) { cfA[nc*2] = bbase2[nc*128]; cfA[nc*2+1] = bbase2[nc*128 + 64]; }
  #pragma unroll 1
  for (int jj = 0; jj < 4; ++jj) {
    const int j0 = jj * 2;
    {
      const uint4* bp = bbase2 + (size_t)(j0 + 1) * 256;
      #pragma unroll
      for (int nc = 0; nc < 2; ++nc) { cfB[nc*2] = bp[nc*128]; cfB[nc*2+1] = bp[nc*128 + 64]; }
    }
    l2step(j0, cfA);
    {
      const uint4* bp = bbase2 + (size_t)(j0 + 2) * 256;
      #pragma unroll
      for (int nc = 0; nc < 2; ++nc) { cfA[nc*2] = bp[nc*128]; cfA[nc*2+1] = bp[nc*128 + 64]; }
    }
    l2step(j0 + 1, cfB);
  }
  l2step(8, cfA);

  const float* wf = finw + sid * 64;
  {
    float w0 = wf[lc], w1v = wf[32 + lc];
    float pz = 0.f;
    #pragma unroll
    for (int r = 0; r < 16; ++r) pz += acc2[0][r] * w0 + acc2[1][r] * w1v;
    #pragma unroll
    for (int off = 32; off > 0; off >>= 1) pz += __shfl_down(pz, off, 64);
    if (l == 0) redw[wave] = pz;
  }
  __syncthreads();
  if (wave == 0) {
    float v = (l < 8) ? redw[l] : 0.f;
    v += 32.f * b2[l] * wf[l];        // bias term over this block's 32 rows
    #pragma unroll
    for (int off = 32; off > 0; off >>= 1) v += __shfl_down(v, off, 64);
    if (l == 0) {
      float contrib = v * (1.0f / 1024.0f);
      if (sid == 0 && (m2 & 31) == 0) contrib += finb[0];  // finb added once per batch
      atomicAdd(&out[m2 >> 5], contrib);
    }
  }
}

extern "C" void kernel_launch(void* const* d_in, const int* in_sizes, int n_in,
                              void* d_out, int out_size, void* d_ws, size_t ws_size,
                              hipStream_t stream)
{
  (void)in_sizes; (void)n_in; (void)out_size; (void)ws_size;
  const float* x    = (const float*)d_in[0];
  const float* y    = (const float*)d_in[1];
  const float* bw1x = (const float*)d_in[2];
  const float* bb1x = (const float*)d_in[3];
  const float* sw1x = (const float*)d_in[4];
  const float* sb1x = (const float*)d_in[5];
  const float* bw2x = (const float*)d_in[6];
  const float* bb2x = (const float*)d_in[7];
  const float* sw2x = (const float*)d_in[8];
  const float* sb2x = (const float*)d_in[9];
  const float* bw1y = (const float*)d_in[10];
  const float* bb1y = (const float*)d_in[11];
  const float* sw1y = (const float*)d_in[12];
  const float* sb1y = (const float*)d_in[13];
  const float* bw2y = (const float*)d_in[14];
  const float* bb2y = (const float*)d_in[15];
  const float* sw2y = (const float*)d_in[16];
  const float* sb2y = (const float*)d_in[17];
  const float* finw = (const float*)d_in[18];
  const float* finb = (const float*)d_in[19];

  char* ws = (char*)d_ws;
  uint4* B1fx = (uint4*)(ws);                       // 1179648 B
  uint4* B1fy = (uint4*)(ws + 1179648);
  uint4* B2fx = (uint4*)(ws + 2359296);             // 294912 B
  uint4* B2fy = (uint4*)(ws + 2654208);
  float* hp   = (float*)(ws + 2949120);             // 8 MB
  float* b1x  = (float*)(ws + 2949120 + 8388608);
  float* b1y  = b1x + 128;
  float* b2x  = b1y + 128;
  float* b2y  = b2x + 64;

  hipMemsetAsync(d_out, 0, 4 * sizeof(float), stream);

  int prep_total = 2 * 36864 + 2 * 9216 + 384;      // 92544
  int prep_blocks = (prep_total + 255) / 256;
  hipLaunchKernelGGL(prep_frags, dim3(prep_blocks), dim3(256), 0, stream,
                     bw1x, sw1x, bb1x, sb1x, bw2x, sw2x, bb2x, sb2x,
                     bw1y, sw1y, bb1y, sb1y, bw2y, sw2y, bb2y, sb2y,
                     B1fx, B1fy, B2fx, B2fy, b1x, b1y, b2x, b2y);

  hipLaunchKernelGGL(phase1_kernel, dim3(256), dim3(512), 0, stream,
                     x, y, B1fx, B1fy, hp);

  hipLaunchKernelGGL(phase2_kernel, dim3(256), dim3(512), 0, stream,
                     B2fx, B2fy, hp, b1x, b1y, b2x, b2y, finw, finb,
                     (float*)d_out);
}

// Round 9
// 41.217 us; speedup vs baseline: 6.0925x; 1.1915x over previous
//
#include <hip/hip_runtime.h>

typedef __attribute__((ext_vector_type(8))) short short8;
typedef __attribute__((ext_vector_type(16))) float floatx16;

// B1 frag layout: per sid, q = (ds*9 + j)*4 + nc  (ds in [0,16), j in [0,9), nc in [0,4))
//   uint4 slot = q*128 + p*64 + l   (p = 0 hi, 1 lo; l = lane)
// B2 frag layout: per sid, q2 = (w*9 + j)*2 + nc (w in [0,8), nc in [0,2))
//   uint4 slot = q2*128 + p*64 + l

__device__ __forceinline__ unsigned short f2bf(float f) {
  union { float f; unsigned u; } v; v.f = f;
  unsigned r = v.u + 0x7fffu + ((v.u >> 16) & 1u);
  return (unsigned short)(r >> 16);
}
__device__ __forceinline__ float bf2f(unsigned short h) {
  union { unsigned u; float f; } v; v.u = ((unsigned)h) << 16;
  return v.f;
}

__global__ __launch_bounds__(512) void prep_frags(
    const float* __restrict__ bw1x, const float* __restrict__ sw1x,
    const float* __restrict__ bb1x, const float* __restrict__ sb1x,
    const float* __restrict__ bw2x, const float* __restrict__ sw2x,
    const float* __restrict__ bb2x, const float* __restrict__ sb2x,
    const float* __restrict__ bw1y, const float* __restrict__ sw1y,
    const float* __restrict__ bb1y, const float* __restrict__ sb1y,
    const float* __restrict__ bw2y, const float* __restrict__ sw2y,
    const float* __restrict__ bb2y, const float* __restrict__ sb2y,
    uint4* __restrict__ B1fx, uint4* __restrict__ B1fy,
    uint4* __restrict__ B2fx, uint4* __restrict__ B2fy,
    float* __restrict__ b1x, float* __restrict__ b1y,
    float* __restrict__ b2x, float* __restrict__ b2y,
    int* __restrict__ cnt)
{
  int idx = blockIdx.x * 512 + threadIdx.x;
  if (idx < 2 * 36864) {                       // B1: 2 sids x 576 q x 64 l
    int sid = idx / 36864;
    int rem = idx - sid * 36864;
    int q = rem >> 6, l = rem & 63;
    int nc = q & 3, t9 = q >> 2;
    int j = t9 % 9, ds = t9 / 9;
    const float* bw = sid ? bw1y : bw1x;
    const float* sw = sid ? sw1y : sw1x;
    uint4* dst = sid ? B1fy : B1fx;
    int o = nc * 32 + (l & 31);
    int dbase = ds * 16 + (l >> 5) * 8;
    unsigned short eh[8], el[8];
    #pragma unroll
    for (int i = 0; i < 8; ++i) {
      int d = dbase + i;
      float wv = (j == 0) ? bw[o * 256 + d] : sw[o * 2048 + d * 8 + (j - 1)];
      unsigned short hi = f2bf(wv);
      eh[i] = hi;
      el[i] = f2bf(wv - bf2f(hi));
    }
    uint4 oh, ol;
    oh.x = (unsigned)eh[0] | ((unsigned)eh[1] << 16);
    oh.y = (unsigned)eh[2] | ((unsigned)eh[3] << 16);
    oh.z = (unsigned)eh[4] | ((unsigned)eh[5] << 16);
    oh.w = (unsigned)eh[6] | ((unsigned)eh[7] << 16);
    ol.x = (unsigned)el[0] | ((unsigned)el[1] << 16);
    ol.y = (unsigned)el[2] | ((unsigned)el[3] << 16);
    ol.z = (unsigned)el[4] | ((unsigned)el[5] << 16);
    ol.w = (unsigned)el[6] | ((unsigned)el[7] << 16);
    dst[q * 128 + l]      = oh;
    dst[q * 128 + 64 + l] = ol;
  } else if (idx < 2 * 36864 + 2 * 9216) {     // B2: 2 sids x 144 q2 x 64 l
    int i2 = idx - 2 * 36864;
    int sid = i2 / 9216;
    int rem = i2 - sid * 9216;
    int q2 = rem >> 6, l = rem & 63;
    int nc = q2 & 1, t9 = q2 >> 1;
    int j = t9 % 9, w = t9 / 9;
    const float* bw = sid ? bw2y : bw2x;
    const float* sw = sid ? sw2y : sw2x;
    uint4* dst = sid ? B2fy : B2fx;
    int o = nc * 32 + (l & 31);
    int dbase = w * 16 + (l >> 5) * 8;
    unsigned short eh[8], el[8];
    #pragma unroll
    for (int i = 0; i < 8; ++i) {
      int d = dbase + i;
      float wv = (j == 0) ? bw[o * 128 + d] : sw[o * 1024 + d * 8 + (j - 1)];
      unsigned short hi = f2bf(wv);
      eh[i] = hi;
      el[i] = f2bf(wv - bf2f(hi));
    }
    uint4 oh, ol;
    oh.x = (unsigned)eh[0] | ((unsigned)eh[1] << 16);
    oh.y = (unsigned)eh[2] | ((unsigned)eh[3] << 16);
    oh.z = (unsigned)eh[4] | ((unsigned)eh[5] << 16);
    oh.w = (unsigned)eh[6] | ((unsigned)eh[7] << 16);
    ol.x = (unsigned)el[0] | ((unsigned)el[1] << 16);
    ol.y = (unsigned)el[2] | ((unsigned)el[3] << 16);
    ol.z = (unsigned)el[4] | ((unsigned)el[5] << 16);
    ol.w = (unsigned)el[6] | ((unsigned)el[7] << 16);
    dst[q2 * 128 + l]      = oh;
    dst[q2 * 128 + 64 + l] = ol;
  } else {
    int i2 = idx - (2 * 36864 + 2 * 9216);
    if (i2 < 128)      b1x[i2]       = bb1x[i2]       + sb1x[i2];
    else if (i2 < 256) b1y[i2 - 128] = bb1y[i2 - 128] + sb1y[i2 - 128];
    else if (i2 < 320) b2x[i2 - 256] = bb2x[i2 - 256] + sb2x[i2 - 256];
    else if (i2 < 384) b2y[i2 - 320] = bb2y[i2 - 320] + sb2y[i2 - 320];
    else if (i2 < 388) cnt[i2 - 384] = 0;
  }
}

// ---------- fused: both layers + last-block finish; block = (sid, 32-row tile m)
__global__ __launch_bounds__(512) void fused_kernel(
    const float* __restrict__ Xx, const float* __restrict__ Xy,
    const uint4* __restrict__ B1fx, const uint4* __restrict__ B1fy,
    const uint4* __restrict__ B2fx, const uint4* __restrict__ B2fy,
    const float* __restrict__ b1x_, const float* __restrict__ b1y_,
    const float* __restrict__ b2x_, const float* __restrict__ b2y_,
    const float* __restrict__ finw, const float* __restrict__ finb,
    float* __restrict__ partial, int* __restrict__ cnt,
    float* __restrict__ out)
{
  __shared__ __align__(16) char smem[51232];
  float* xsh  = (float*)smem;               // 32*264 floats = 33792 B
  float* S0   = (float*)smem;               // 16 KB (alias; used after xr read)
  float* S1   = (float*)(smem + 16384);     // 16 KB
  float* h1s  = (float*)(smem + 33792);     // 32*136 floats = 17408 B
  float* redw = (float*)(smem + 51200);     // 8 floats

  const int t    = threadIdx.x;
  const int bid  = blockIdx.x;
  const int sid  = bid >> 7;
  const int m    = bid & 127;
  const int wave = t >> 6;
  const int l    = t & 63;
  const int lc   = l & 31;
  const int lk   = l >> 5;

  const float* X  = sid ? Xy : Xx;
  const uint4* B1 = sid ? B1fy : B1fx;
  const uint4* B2 = sid ? B2fy : B2fx;
  const float* b1 = sid ? b1y_ : b1x_;
  const float* b2 = sid ? b2y_ : b2x_;

  // ---- stage x tile: 32 rows x 256, coalesced ----
  {
    int row = t >> 4, col = (t & 15) * 16;
    const float* src = X + (size_t)(m * 32 + row) * 256 + col;
    #pragma unroll
    for (int q = 0; q < 4; ++q)
      *(float4*)(xsh + row * 264 + col + q * 4) = *(const float4*)(src + q * 4);
  }
  __syncthreads();

  // per-lane A data: row lc, dims for ds0 = 2*wave and ds1 = 2*wave+1
  float xr0[8], xr1[8];
  {
    int cb = wave * 32 + lk * 8;
    float4 v0 = *(const float4*)(xsh + lc * 264 + cb);
    float4 v1 = *(const float4*)(xsh + lc * 264 + cb + 4);
    float4 u0 = *(const float4*)(xsh + lc * 264 + cb + 16);
    float4 u1 = *(const float4*)(xsh + lc * 264 + cb + 20);
    xr0[0]=v0.x; xr0[1]=v0.y; xr0[2]=v0.z; xr0[3]=v0.w;
    xr0[4]=v1.x; xr0[5]=v1.y; xr0[6]=v1.z; xr0[7]=v1.w;
    xr1[0]=u0.x; xr1[1]=u0.y; xr1[2]=u0.z; xr1[3]=u0.w;
    xr1[4]=u1.x; xr1[5]=u1.y; xr1[6]=u1.z; xr1[7]=u1.w;
  }
  __syncthreads();   // xsh dead; S0/S1 free

  // ================= layer 1 =================
  floatx16 acc[4] = {};
  #pragma unroll 1
  for (int j = 0; j < 9; ++j) {
    #pragma unroll
    for (int ds2 = 0; ds2 < 2; ++ds2) {
      const int ds = wave * 2 + ds2;
      const uint4* bp = B1 + (size_t)((ds * 9 + j) * 4) * 128 + l;
      uint4 bf[8];
      #pragma unroll
      for (int nc = 0; nc < 4; ++nc) {
        bf[nc * 2]     = bp[nc * 128];
        bf[nc * 2 + 1] = bp[nc * 128 + 64];
      }
      const float* xr = ds2 ? xr1 : xr0;
      float f[8];
      if (j == 0) {
        #pragma unroll
        for (int i = 0; i < 8; ++i)
          f[i] = __fdividef(xr[i], 1.f + __expf(-xr[i]));
      } else {
        float g = -2.f + (float)(j - 1) * (4.f / 7.f);
        #pragma unroll
        for (int i = 0; i < 8; ++i) {
          float z = (xr[i] - g) * 1.75f;
          f[i] = __expf(-z * z);
        }
      }
      short8 a;
      #pragma unroll
      for (int i = 0; i < 8; ++i) a[i] = (short)f2bf(f[i]);
      #pragma unroll
      for (int nc = 0; nc < 4; ++nc) {
        short8 bh = __builtin_bit_cast(short8, bf[nc * 2]);
        short8 bl = __builtin_bit_cast(short8, bf[nc * 2 + 1]);
        acc[nc] = __builtin_amdgcn_mfma_f32_32x32x16_bf16(a, bh, acc[nc], 0, 0, 0);
        acc[nc] = __builtin_amdgcn_mfma_f32_32x32x16_bf16(a, bl, acc[nc], 0, 0, 0);
      }
    }
  }

  // ---- cross-wave K reduction: race-free 2-buffer tree (32x128 tile) ----
  auto st = [&](float* Sb) {
    #pragma unroll
    for (int nc = 0; nc < 4; ++nc)
      #pragma unroll
      for (int r = 0; r < 16; ++r) {
        int row = (r & 3) + 8 * (r >> 2) + 4 * lk;
        Sb[row * 128 + nc * 32 + lc] = acc[nc][r];
      }
  };
  auto ad = [&](const float* Sb) {
    #pragma unroll
    for (int nc = 0; nc < 4; ++nc)
      #pragma unroll
      for (int r = 0; r < 16; ++r) {
        int row = (r & 3) + 8 * (r >> 2) + 4 * lk;
        acc[nc][r] += Sb[row * 128 + nc * 32 + lc];
      }
  };
  __syncthreads();
  if (wave == 1) st(S0);
  if (wave == 3) st(S1);
  __syncthreads();
  if (wave == 0) ad(S0);
  if (wave == 2) ad(S1);
  __syncthreads();
  if (wave == 5) st(S0);
  if (wave == 7) st(S1);
  __syncthreads();
  if (wave == 4) ad(S0);
  if (wave == 6) ad(S1);
  __syncthreads();
  if (wave == 2) st(S0);
  if (wave == 6) st(S1);
  __syncthreads();
  if (wave == 0) ad(S0);
  if (wave == 4) ad(S1);
  __syncthreads();
  if (wave == 4) st(S0);
  __syncthreads();
  if (wave == 0) {
    ad(S0);
    #pragma unroll
    for (int nc = 0; nc < 4; ++nc)
      #pragma unroll
      for (int r = 0; r < 16; ++r) {
        int row = (r & 3) + 8 * (r >> 2) + 4 * lk;
        int col = nc * 32 + lc;
        h1s[row * 136 + col] = acc[nc][r] + b1[col];
      }
  }
  __syncthreads();

  // ================= layer 2: wave owns 16 h1 dims =================
  float hr[8];
  {
    int cb = wave * 16 + lk * 8;
    float4 v0 = *(const float4*)(h1s + lc * 136 + cb);
    float4 v1 = *(const float4*)(h1s + lc * 136 + cb + 4);
    hr[0]=v0.x; hr[1]=v0.y; hr[2]=v0.z; hr[3]=v0.w;
    hr[4]=v1.x; hr[5]=v1.y; hr[6]=v1.z; hr[7]=v1.w;
  }

  floatx16 acc2[2] = {};
  #pragma unroll 1
  for (int j = 0; j < 9; ++j) {
    const uint4* bp = B2 + (size_t)((wave * 9 + j) * 2) * 128 + l;
    uint4 bf[4];
    #pragma unroll
    for (int nc = 0; nc < 2; ++nc) {
      bf[nc * 2]     = bp[nc * 128];
      bf[nc * 2 + 1] = bp[nc * 128 + 64];
    }
    float f[8];
    if (j == 0) {
      #pragma unroll
      for (int i = 0; i < 8; ++i)
        f[i] = __fdividef(hr[i], 1.f + __expf(-hr[i]));
    } else {
      float g = -2.f + (float)(j - 1) * (4.f / 7.f);
      #pragma unroll
      for (int i = 0; i < 8; ++i) {
        float z = (hr[i] - g) * 1.75f;
        f[i] = __expf(-z * z);
      }
    }
    short8 a;
    #pragma unroll
    for (int i = 0; i < 8; ++i) a[i] = (short)f2bf(f[i]);
    #pragma unroll
    for (int nc = 0; nc < 2; ++nc) {
      short8 bh = __builtin_bit_cast(short8, bf[nc * 2]);
      short8 bl = __builtin_bit_cast(short8, bf[nc * 2 + 1]);
      acc2[nc] = __builtin_amdgcn_mfma_f32_32x32x16_bf16(a, bh, acc2[nc], 0, 0, 0);
      acc2[nc] = __builtin_amdgcn_mfma_f32_32x32x16_bf16(a, bl, acc2[nc], 0, 0, 0);
    }
  }

  // ---- per-wave dot with final_w; cross-wave scalar sum ----
  const float* wf = finw + sid * 64;
  {
    float w0 = wf[lc], w1v = wf[32 + lc];
    float pz = 0.f;
    #pragma unroll
    for (int r = 0; r < 16; ++r) pz += acc2[0][r] * w0 + acc2[1][r] * w1v;
    #pragma unroll
    for (int off = 32; off > 0; off >>= 1) pz += __shfl_down(pz, off, 64);
    if (l == 0) redw[wave] = pz;
  }
  __syncthreads();

  // ---- block partial + last-block-per-batch finish ----
  if (wave == 0) {
    const int b    = m >> 5;                 // batch
    const int slot = sid * 32 + (m & 31);    // 64 slots per batch
    float v = (l < 8) ? redw[l] : 0.f;
    v += 32.f * b2[l] * wf[l];               // bias term over this block's 32 rows
    #pragma unroll
    for (int off = 32; off > 0; off >>= 1) v += __shfl_down(v, off, 64);
    int old = 0;
    if (l == 0) {
      partial[b * 64 + slot] = v;
      __threadfence();
      old = atomicAdd(&cnt[b], 1);
    }
    int bc = __shfl(old, 0, 64);
    if (bc == 63) {                          // last block of this batch
      float pv = atomicAdd(&partial[b * 64 + l], 0.f);  // coherent read
      #pragma unroll
      for (int off = 32; off > 0; off >>= 1) pv += __shfl_down(pv, off, 64);
      if (l == 0) out[b] = finb[0] + pv * (1.0f / 1024.0f);
    }
  }
}

extern "C" void kernel_launch(void* const* d_in, const int* in_sizes, int n_in,
                              void* d_out, int out_size, void* d_ws, size_t ws_size,
                              hipStream_t stream)
{
  (void)in_sizes; (void)n_in; (void)out_size; (void)ws_size;
  const float* x    = (const float*)d_in[0];
  const float* y    = (const float*)d_in[1];
  const float* bw1x = (const float*)d_in[2];
  const float* bb1x = (const float*)d_in[3];
  const float* sw1x = (const float*)d_in[4];
  const float* sb1x = (const float*)d_in[5];
  const float* bw2x = (const float*)d_in[6];
  const float* bb2x = (const float*)d_in[7];
  const float* sw2x = (const float*)d_in[8];
  const float* sb2x = (const float*)d_in[9];
  const float* bw1y = (const float*)d_in[10];
  const float* bb1y = (const float*)d_in[11];
  const float* sw1y = (const float*)d_in[12];
  const float* sb1y = (const float*)d_in[13];
  const float* bw2y = (const float*)d_in[14];
  const float* bb2y = (const float*)d_in[15];
  const float* sw2y = (const float*)d_in[16];
  const float* sb2y = (const float*)d_in[17];
  const float* finw = (const float*)d_in[18];
  const float* finb = (const float*)d_in[19];

  char* ws = (char*)d_ws;
  uint4* B1fx = (uint4*)(ws);                       // 1179648 B
  uint4* B1fy = (uint4*)(ws + 1179648);
  uint4* B2fx = (uint4*)(ws + 2359296);             // 294912 B
  uint4* B2fy = (uint4*)(ws + 2654208);
  float* b1x  = (float*)(ws + 2949120);
  float* b1y  = b1x + 128;
  float* b2x  = b1y + 128;
  float* b2y  = b2x + 64;
  float* partial = b2y + 64;                        // 256 floats
  int*   cnt  = (int*)(partial + 256);              // 4 ints

  int prep_total = 2 * 36864 + 2 * 9216 + 388;      // 92548
  int prep_blocks = (prep_total + 511) / 512;
  hipLaunchKernelGGL(prep_frags, dim3(prep_blocks), dim3(512), 0, stream,
                     bw1x, sw1x, bb1x, sb1x, bw2x, sw2x, bb2x, sb2x,
                     bw1y, sw1y, bb1y, sb1y, bw2y, sw2y, bb2y, sb2y,
                     B1fx, B1fy, B2fx, B2fy, b1x, b1y, b2x, b2y, cnt);

  hipLaunchKernelGGL(fused_kernel, dim3(256), dim3(512), 0, stream,
                     x, y, B1fx, B1fy, B2fx, B2fy, b1x, b1y, b2x, b2y,
                     finw, finb, partial, cnt, (float*)d_out);
}